// Round 3
// baseline (614.960 us; speedup 1.0000x reference)
//
#include <hip/hip_runtime.h>
#include <math.h>

#define SLOPE 0.2f
#define LOG2E 1.4426950408889634f

// DPP add over 16-lane head group: quad_perm xor1/xor2, row_half_mirror, row_mirror.
#define DPP_ADD(x, ctrl) \
    ((x) + __int_as_float(__builtin_amdgcn_update_dpp( \
        0, __float_as_int(x), (ctrl), 0xF, 0xF, true)))

// ============ CSR build: 2-level binning (round-8) ============
// Round-2 k_place scattered 4B words to random lines of the 16MB col array:
// 69 MB HBM write, ~1 TB/s random-line regime, 73 us. k_count had the same
// problem (1M random atomics). Now: bucket edges by dst>>7 (128 nodes/bucket,
// ~1280 edges/bucket -> 5KB col window) so every global write stream is
// either sequential (kB2 append) or confined to a hot 5KB window (kB4).
// Payload shrinks to one packed int/edge: (src<<8) | (dst & 127).

#define BSH 7                 // bucket shift: 128 nodes per bucket
#define NPB 128               // nodes per bucket

// kB1: bucket histogram. LDS hist per block, merged with one atomic per
// nonzero bucket per block (256 blocks x <=1024 buckets).
__global__ __launch_bounds__(256) void kB1(const int* __restrict__ ei,
                                           int* __restrict__ bcnt,
                                           int E, int nbk) {
    __shared__ int h[1024];
    int t = threadIdx.x;
    if (nbk <= 1024) {
        for (int i = t; i < nbk; i += 256) h[i] = 0;
        __syncthreads();
        for (int e = blockIdx.x * 256 + t; e < E; e += gridDim.x * 256)
            atomicAdd(&h[ei[E + e] >> BSH], 1);
        __syncthreads();
        for (int i = t; i < nbk; i += 256)
            if (h[i]) atomicAdd(&bcnt[i], h[i]);
    } else {   // fallback for huge N (not hit at N=100k)
        for (int e = blockIdx.x * 256 + t; e < E; e += gridDim.x * 256)
            atomicAdd(&bcnt[ei[E + e] >> BSH], 1);
    }
}

// kB2: scatter packed edges into bucket append-regions. Writes within a
// bucket are consecutive -> L2 lines fill completely before eviction.
__global__ __launch_bounds__(256) void kB2(const int* __restrict__ ei,
                                           int* __restrict__ bcur,
                                           int* __restrict__ pairs, int E) {
    int e = blockIdx.x * 256 + threadIdx.x;
    if (e < E) {
        int s = ei[e], d = ei[E + e];
        int slot = atomicAdd(&bcur[d >> BSH], 1);
        pairs[slot] = (s << 8) | (d & (NPB - 1));
    }
}

// kB3: per-bucket degree histogram in LDS (replaces 1M global atomics of
// the old k_count). Block b owns nodes [b*128, b*128+128).
__global__ __launch_bounds__(256) void kB3(const int* __restrict__ boff,
                                           const int* __restrict__ bend,
                                           const int* __restrict__ pairs,
                                           int* __restrict__ deg, int n) {
    __shared__ int sdeg[NPB];
    int t = threadIdx.x, b = blockIdx.x;
    if (t < NPB) sdeg[t] = 0;
    __syncthreads();
    int s0 = boff[b], s1 = bend[b];
    for (int i = s0 + t; i < s1; i += 256)
        atomicAdd(&sdeg[pairs[i] & (NPB - 1)], 1);
    __syncthreads();
    int node = b * NPB + t;
    if (t < NPB && node < n) deg[node] = sdeg[t];
}

// kB4: per-bucket placement with LDS cursors. col writes confined to the
// bucket's ~5KB window -> lines fully dirtied -> ~4MB HBM write total.
__global__ __launch_bounds__(256) void kB4(const int* __restrict__ boff,
                                           const int* __restrict__ bend,
                                           const int* __restrict__ pairs,
                                           const int* __restrict__ rp,
                                           int* __restrict__ col, int n) {
    __shared__ int scur[NPB];
    int t = threadIdx.x, b = blockIdx.x;
    if (t < NPB) {
        int node = b * NPB + t;
        scur[t] = (node < n) ? rp[node] : 0;
    }
    __syncthreads();
    int s0 = boff[b], s1 = bend[b];
    for (int i = s0 + t; i < s1; i += 256) {
        int p = pairs[i];
        int slot = atomicAdd(&scur[p & (NPB - 1)], 1);
        col[slot] = p & ~(unsigned)(NPB * 2 - 1);   // recover src<<8 (bit7=0)
    }
}

// ---------------- scans ----------------
// pad4=1: round degree up to multiple of 4 (k_node reads col via aligned
// int4). pad4=0: plain exclusive scan (bucket offsets).

__global__ __launch_bounds__(256) void k_scan1(const int* __restrict__ deg,
                                               int* __restrict__ rp,
                                               int* __restrict__ blk, int n,
                                               int pad4) {
    __shared__ int sd[256];
    int t = threadIdx.x;
    int base = blockIdx.x * 1024 + t * 4;
    int v0 = 0, v1 = 0, v2 = 0, v3 = 0;
    if (base + 0 < n) v0 = deg[base + 0];
    if (base + 1 < n) v1 = deg[base + 1];
    if (base + 2 < n) v2 = deg[base + 2];
    if (base + 3 < n) v3 = deg[base + 3];
    if (pad4) {
        v0 = (v0 + 3) & ~3; v1 = (v1 + 3) & ~3;
        v2 = (v2 + 3) & ~3; v3 = (v3 + 3) & ~3;
    }
    int s = v0 + v1 + v2 + v3;
    sd[t] = s;
    __syncthreads();
    for (int off = 1; off < 256; off <<= 1) {
        int x = (t >= off) ? sd[t - off] : 0;
        __syncthreads();
        sd[t] += x;
        __syncthreads();
    }
    int ex = sd[t] - s;
    if (t == 255) blk[blockIdx.x] = sd[255];
    if (base + 0 < n) rp[base + 0] = ex; ex += v0;
    if (base + 1 < n) rp[base + 1] = ex; ex += v1;
    if (base + 2 < n) rp[base + 2] = ex; ex += v2;
    if (base + 3 < n) rp[base + 3] = ex;
}

__global__ __launch_bounds__(256) void k_scan2(int* __restrict__ blk, int nblk) {
    __shared__ int sd[256];
    int t = threadIdx.x;
    int v = (t < nblk) ? blk[t] : 0;
    sd[t] = v;
    __syncthreads();
    for (int off = 1; off < 256; off <<= 1) {
        int x = (t >= off) ? sd[t - off] : 0;
        __syncthreads();
        sd[t] += x;
        __syncthreads();
    }
    if (t < nblk) blk[t] = sd[t] - v;
}

// Adds block offsets; also emits a cursor copy (bucket claim cursor for kB2).
__global__ __launch_bounds__(256) void k_scan3(int* __restrict__ rp,
                                               int* __restrict__ cur,
                                               const int* __restrict__ blk,
                                               int n) {
    int t = threadIdx.x;
    int base = blockIdx.x * 1024 + t * 4;
    int off = blk[blockIdx.x];
    #pragma unroll
    for (int i = 0; i < 4; i++) {
        int idx = base + i;
        if (idx < n) {
            int v = rp[idx] + off;
            rp[idx] = v;
            cur[idx] = v;
        }
    }
}

// ---------------- GEMM: xl = in @ Wl, xr = in @ Wr ----------------
// Round-7 structure (verified: dropped out of top-5, ~20 us/dispatch).
// x tile staged through LDS with fully-coalesced loads; K-loop reads LDS only.
//   block = 64 rows x 128 cols; thread = 4 rows (stride 16) x 8 cols
//   LDS = 32 KB sW + 17 KB sx -> 3 blocks/CU; sW reads broadcast, sx 2-way.

__global__ __launch_bounds__(256) void k_gemm(const float* __restrict__ in,
                                              const float* __restrict__ Wl,
                                              const float* __restrict__ Wr,
                                              float* __restrict__ xl,
                                              float* __restrict__ xr, int n) {
    __shared__ float4 sW[64 * 32];   // [k][jq]: jq<16 -> Wl cols, else Wr
    __shared__ float  sx[64 * 68];   // 64 rows, pad-68 floats (272 B) stride

    int t = threadIdx.x;
    int base = blockIdx.x * 64;

    float4 xs[4];
    int xrow[4], xkq[4];
    #pragma unroll
    for (int s = 0; s < 4; s++) {
        int i = t + 256 * s;           // 1024 float4 = 64 rows x 16 quads
        int row = i >> 4, kq = i & 15;
        int g = base + row;
        if (g > n - 1) g = n - 1;      // clamp: always-valid load, no UB
        xs[s] = *(const float4*)(in + (size_t)g * 64 + kq * 4);
        xrow[s] = row; xkq[s] = kq;
    }
    for (int i = t; i < 2048; i += 256) {
        int k = i >> 5, jg = i & 31;
        const float* src = (jg < 16) ? (Wl + k * 64 + jg * 4)
                                     : (Wr + k * 64 + (jg - 16) * 4);
        sW[i] = *(const float4*)src;
    }
    #pragma unroll
    for (int s = 0; s < 4; s++)
        *(float4*)(sx + xrow[s] * 68 + xkq[s] * 4) = xs[s];
    __syncthreads();

    int rt = t & 15;   // rows rt, rt+16, rt+32, rt+48
    int ct = t >> 4;   // 16 col tiles of 8 cols (2 quads)
    const float* sxp = sx + rt * 68;

    float4 acc[4][2];
    #pragma unroll
    for (int r = 0; r < 4; r++)
        #pragma unroll
        for (int j = 0; j < 2; j++) acc[r][j] = make_float4(0.f, 0.f, 0.f, 0.f);

    #pragma unroll 1
    for (int k0 = 0; k0 < 64; k0 += 4) {
        float4 xv[4];
        #pragma unroll
        for (int r = 0; r < 4; r++)
            xv[r] = *(const float4*)(sxp + r * (16 * 68) + k0);
        #pragma unroll
        for (int kk = 0; kk < 4; kk++) {
            float4 w0 = sW[(k0 + kk) * 32 + ct * 2 + 0];
            float4 w1 = sW[(k0 + kk) * 32 + ct * 2 + 1];
            #pragma unroll
            for (int r = 0; r < 4; r++) {
                float xk = (kk == 0) ? xv[r].x : (kk == 1) ? xv[r].y
                         : (kk == 2) ? xv[r].z : xv[r].w;
                acc[r][0].x += xk * w0.x;
                acc[r][0].y += xk * w0.y;
                acc[r][0].z += xk * w0.z;
                acc[r][0].w += xk * w0.w;
                acc[r][1].x += xk * w1.x;
                acc[r][1].y += xk * w1.y;
                acc[r][1].z += xk * w1.z;
                acc[r][1].w += xk * w1.w;
            }
        }
    }

    float* outh = (ct < 8) ? xl : xr;
    int cq = (ct & 7) * 8;
    #pragma unroll
    for (int r = 0; r < 4; r++) {
        int g = base + rt + 16 * r;
        if (g < n) {
            float* dst = outh + (size_t)g * 64 + cq;
            *(float4*)(dst + 0) = acc[r][0];
            *(float4*)(dst + 4) = acc[r][1];
        }
    }
}

// ---------------- node kernel: no-max softmax GATv2 aggregation ----------------
// One wave per node, lane = h*16 + o. Batch-8 software pipeline.
// Pad-4 segments -> col loads are 2x int4 per batch, no clamp math.
// No online max (logits O(1): p std ~0.5, max ~3 over 4M; fp32 exp safe to 88).
// Tail/pad slots masked with p=-inf -> w=0; pad col=0 gathers row 0 (hot line).

__global__ __launch_bounds__(256) void k_node(const float* __restrict__ xl,
                                              const float* __restrict__ xr,
                                              const int* __restrict__ rp,
                                              const int* __restrict__ deg,
                                              const int* __restrict__ col,
                                              const float* __restrict__ A,
                                              const float* __restrict__ Bv,
                                              float* __restrict__ outp,
                                              int n, int relu) {
    int lane = threadIdx.x & 63;
    int node = blockIdx.x * 4 + (threadIdx.x >> 6);
    if (node >= n) return;
    unsigned lane4 = (unsigned)lane * 4u;

    float xr_d = xr[(size_t)node * 64 + lane];
    float a_l = A[lane] * LOG2E;   // exp2-domain logits
    float b_l = Bv[lane];

    int start = rp[node];          // multiple of 4 -> 16B-aligned col reads
    int d = deg[node];
    int nb = (d + 7) >> 3;
    const int* cp = col + start;
    const char* xlb = (const char*)xl;

    float den = 0.f, acc = 0.f;

    auto batch = [&](const float (&v)[8], int valid) {
        float p[8];
        #pragma unroll
        for (int j = 0; j < 8; j++) {
            float s = v[j] + xr_d;
            s = fmaxf(s, SLOPE * s);      // leaky_relu (slope < 1)
            float q = s * a_l;
            q = DPP_ADD(q, 0xB1);         // xor1
            q = DPP_ADD(q, 0x4E);         // xor2  -> quad sums
            q = DPP_ADD(q, 0x141);        // half_mirror
            q = DPP_ADD(q, 0x140);        // mirror -> full 16-lane sum
            p[j] = q;
        }
        if (valid < 8) {                  // wave-uniform; tail only
            #pragma unroll
            for (int j = 0; j < 8; j++)
                if (j >= valid) p[j] = -INFINITY;
        }
        #pragma unroll
        for (int j = 0; j < 8; j++) {
            float w = exp2f(p[j]);        // masked: exp2(-inf)=0
            den += w;
            acc += w * v[j];
        }
    };

    float v[8];
    if (nb > 0) {
        int c[8];
        *(int4*)(c + 0) = *(const int4*)(cp + 0);
        *(int4*)(c + 4) = *(const int4*)(cp + 4);
        #pragma unroll
        for (int j = 0; j < 8; j++)
            v[j] = *(const float*)(xlb + ((unsigned)c[j] + lane4));
    }

    #pragma unroll 1
    for (int b = 0; b < nb - 1; b++) {
        int cN[8];
        float vN[8];
        const int* q = cp + (b + 1) * 8;
        *(int4*)(cN + 0) = *(const int4*)(q + 0);
        *(int4*)(cN + 4) = *(const int4*)(q + 4);
        #pragma unroll
        for (int j = 0; j < 8; j++)
            vN[j] = *(const float*)(xlb + ((unsigned)cN[j] + lane4));

        batch(v, 8);                      // full batch: no masking

        #pragma unroll
        for (int j = 0; j < 8; j++) v[j] = vN[j];
    }

    if (nb > 0) {
        batch(v, d - (nb - 1) * 8);       // 1..8 valid in tail
    }

    float o = acc / (den + 1e-16f) + b_l;
    if (relu) o = fmaxf(o, 0.f);
    outp[(size_t)node * 64 + lane] = o;
}

// ---------------- launcher ----------------

extern "C" void kernel_launch(void* const* d_in, const int* in_sizes, int n_in,
                              void* d_out, int out_size, void* d_ws, size_t ws_size,
                              hipStream_t stream) {
    const float* x = (const float*)d_in[0];
    const int* ei = (const int*)d_in[1];
    int N = in_sizes[0] / 64;
    int E = in_sizes[1] / 2;

    const float* Wl[3] = {(const float*)d_in[2], (const float*)d_in[6], (const float*)d_in[10]};
    const float* Wr[3] = {(const float*)d_in[3], (const float*)d_in[7], (const float*)d_in[11]};
    const float* Av[3] = {(const float*)d_in[4], (const float*)d_in[8], (const float*)d_in[12]};
    const float* Bv[3] = {(const float*)d_in[5], (const float*)d_in[9], (const float*)d_in[13]};

    char* w = (char*)d_ws;
    auto carve = [&](size_t bytes) {
        void* p = (void*)w;
        w += (bytes + 255) & ~(size_t)255;
        return p;
    };
    int NBK = (N + NPB - 1) / NPB;                  // buckets of 128 nodes
    size_t colN = (size_t)E + 3 * (size_t)N + 64;   // pad-4 segments + tail slack
    float* xl    = (float*)carve((size_t)N * 64 * 4);
    float* xr    = (float*)carve((size_t)N * 64 * 4);
    float* h     = (float*)carve((size_t)N * 64 * 4);
    int*   rp    = (int*)carve((size_t)N * 4);
    int*   deg   = (int*)carve((size_t)N * 4);
    int*   cur   = (int*)carve((size_t)N * 4);
    int*   col   = (int*)carve(colN * 4);
    int*   pairs = (int*)carve((size_t)E * 4);
    int*   bcnt  = (int*)carve((size_t)NBK * 4);
    int*   boff  = (int*)carve((size_t)NBK * 4);
    int*   bcur  = (int*)carve((size_t)NBK * 4);
    int*   blk   = (int*)carve(256 * 4);
    int*   blkB  = (int*)carve(256 * 4);

    int nblk1024  = (N + 1023) / 1024;
    int nblkB1024 = (NBK + 1023) / 1024;
    int e1_grid = (E + 255) / 256;
    int gemm_grid = (N + 63) / 64;
    int node_grid = (N + 3) / 4;

    hipMemsetAsync(bcnt, 0, (size_t)NBK * 4, stream);
    hipMemsetAsync(col, 0, colN * 4, stream);   // zeroed padding -> safe masked gathers

    // bucket pass
    kB1<<<256, 256, 0, stream>>>(ei, bcnt, E, NBK);
    k_scan1<<<nblkB1024, 256, 0, stream>>>(bcnt, boff, blkB, NBK, 0);
    k_scan2<<<1, 256, 0, stream>>>(blkB, nblkB1024);
    k_scan3<<<nblkB1024, 256, 0, stream>>>(boff, bcur, blkB, NBK);
    kB2<<<e1_grid, 256, 0, stream>>>(ei, bcur, pairs, E);   // bcur -> bucket ends

    // degrees + row pointers + placement
    kB3<<<NBK, 256, 0, stream>>>(boff, bcur, pairs, deg, N);
    k_scan1<<<nblk1024, 256, 0, stream>>>(deg, rp, blk, N, 1);
    k_scan2<<<1, 256, 0, stream>>>(blk, nblk1024);
    k_scan3<<<nblk1024, 256, 0, stream>>>(rp, cur, blk, N);
    kB4<<<NBK, 256, 0, stream>>>(boff, bcur, pairs, rp, col, N);

    const float* in_l = x;
    for (int l = 0; l < 3; l++) {
        float* out_l = (l == 2) ? (float*)d_out : h;
        int relu = (l < 2) ? 1 : 0;
        k_gemm<<<gemm_grid, 256, 0, stream>>>(in_l, Wl[l], Wr[l], xl, xr, N);
        k_node<<<node_grid, 256, 0, stream>>>(xl, xr, rp, deg, col, Av[l], Bv[l],
                                              out_l, N, relu);
        in_l = h;
    }
}

// Round 4
// 400.355 us; speedup vs baseline: 1.5360x; 1.5360x over previous
//
#include <hip/hip_runtime.h>
#include <math.h>

#define SLOPE 0.2f
#define LOG2E 1.4426950408889634f

// DPP add over 16-lane head group: quad_perm xor1/xor2, row_half_mirror, row_mirror.
#define DPP_ADD(x, ctrl) \
    ((x) + __int_as_float(__builtin_amdgcn_update_dpp( \
        0, __float_as_int(x), (ctrl), 0xF, 0xF, true)))

// ============ CSR build: counting-sort binning (round-9) ============
// Round-3's kB2 claimed slots via global atomics on 782 bucket cursors:
// ~1280 serialized same-address atomics per cursor x ~450cy cross-XCD
// coherence bounce = 237 us (VALUBusy 0.1%). Round-9 removes ALL contended
// global atomics: two-pass counting sort with per-(block,bucket) offsets.
//   kH1: per-block LDS histogram of dst>>8 -> hist[bucket][block] (one
//        write per cell, no global atomics)
//   scan(hist) -> disjoint output runs per (block,bucket)
//   kH2: re-read edges, claim rank via LDS atomic (392 counters, ~3cy),
//        write pairs[run + rank]; runs are L2-resident while hot.
//   kB3/kB4: per-bucket (256 nodes) LDS degree histogram / col placement
//        into a 10-16KB window. pairs = (src<<8)|(dst&255); col = p & ~255
//        recovers the pre-scaled xl byte offset directly.

#define NPB 256               // nodes per bucket (dst >> 8)
#define EPB 8192              // edges per sort block
#define MAXBK 2048            // LDS histogram capacity (N up to 512k)

__global__ __launch_bounds__(256) void kH1(const int* __restrict__ ei,
                                           int* __restrict__ hist,
                                           int E, int nbk, int nblkE) {
    __shared__ int h[MAXBK];
    int t = threadIdx.x, b = blockIdx.x;
    for (int i = t; i < nbk; i += 256) h[i] = 0;
    __syncthreads();
    int e0 = b * EPB, e1 = min(e0 + EPB, E);
    for (int e = e0 + t; e < e1; e += 256)
        atomicAdd(&h[ei[E + e] >> 8], 1);
    __syncthreads();
    for (int i = t; i < nbk; i += 256)
        hist[i * nblkE + b] = h[i];   // hist area ~190KB: stays in L2
}

__global__ __launch_bounds__(256) void kH2(const int* __restrict__ ei,
                                           const int* __restrict__ hs,
                                           int* __restrict__ pairs,
                                           int E, int nbk, int nblkE) {
    __shared__ int soff[MAXBK];       // this block's run starts; LDS-claimed
    int t = threadIdx.x, b = blockIdx.x;
    for (int i = t; i < nbk; i += 256) soff[i] = hs[i * nblkE + b];
    __syncthreads();
    int e0 = b * EPB, e1 = min(e0 + EPB, E);
    for (int e = e0 + t; e < e1; e += 256) {
        int s = ei[e], d = ei[E + e];
        int slot = atomicAdd(&soff[d >> 8], 1);   // LDS atomic: no contention
        pairs[slot] = (s << 8) | (d & (NPB - 1));
    }
}

// kB3: per-bucket degree histogram in LDS. Block b owns nodes [b*256, b*256+256).
__global__ __launch_bounds__(256) void kB3(const int* __restrict__ hs,
                                           const int* __restrict__ pairs,
                                           int* __restrict__ deg,
                                           int E, int nbk, int nblkE, int n) {
    __shared__ int sdeg[NPB];
    int t = threadIdx.x, b = blockIdx.x;
    sdeg[t] = 0;
    __syncthreads();
    int s0 = hs[b * nblkE];
    int s1 = (b + 1 < nbk) ? hs[(b + 1) * nblkE] : E;
    for (int i = s0 + t; i < s1; i += 256)
        atomicAdd(&sdeg[pairs[i] & (NPB - 1)], 1);
    __syncthreads();
    int node = b * NPB + t;
    if (node < n) deg[node] = sdeg[t];
}

// kB4: per-bucket placement with LDS cursors; col writes land in the
// bucket's ~10-16KB window -> lines fully dirtied before eviction.
__global__ __launch_bounds__(256) void kB4(const int* __restrict__ hs,
                                           const int* __restrict__ pairs,
                                           const int* __restrict__ rp,
                                           int* __restrict__ col,
                                           int E, int nbk, int nblkE, int n) {
    __shared__ int scur[NPB];
    int t = threadIdx.x, b = blockIdx.x;
    int node = b * NPB + t;
    scur[t] = (node < n) ? rp[node] : 0;
    __syncthreads();
    int s0 = hs[b * nblkE];
    int s1 = (b + 1 < nbk) ? hs[(b + 1) * nblkE] : E;
    for (int i = s0 + t; i < s1; i += 256) {
        int p = pairs[i];
        int slot = atomicAdd(&scur[p & (NPB - 1)], 1);
        col[slot] = p & ~(NPB - 1);   // recover src<<8
    }
}

// ---------------- scans ----------------
// pad4=1: round values up to multiple of 4 (k_node reads col via aligned
// int4). pad4=0: plain exclusive scan (hist offsets).

__global__ __launch_bounds__(256) void k_scan1(const int* __restrict__ deg,
                                               int* __restrict__ rp,
                                               int* __restrict__ blk, int n,
                                               int pad4) {
    __shared__ int sd[256];
    int t = threadIdx.x;
    int base = blockIdx.x * 1024 + t * 4;
    int v0 = 0, v1 = 0, v2 = 0, v3 = 0;
    if (base + 0 < n) v0 = deg[base + 0];
    if (base + 1 < n) v1 = deg[base + 1];
    if (base + 2 < n) v2 = deg[base + 2];
    if (base + 3 < n) v3 = deg[base + 3];
    if (pad4) {
        v0 = (v0 + 3) & ~3; v1 = (v1 + 3) & ~3;
        v2 = (v2 + 3) & ~3; v3 = (v3 + 3) & ~3;
    }
    int s = v0 + v1 + v2 + v3;
    sd[t] = s;
    __syncthreads();
    for (int off = 1; off < 256; off <<= 1) {
        int x = (t >= off) ? sd[t - off] : 0;
        __syncthreads();
        sd[t] += x;
        __syncthreads();
    }
    int ex = sd[t] - s;
    if (t == 255) blk[blockIdx.x] = sd[255];
    if (base + 0 < n) rp[base + 0] = ex; ex += v0;
    if (base + 1 < n) rp[base + 1] = ex; ex += v1;
    if (base + 2 < n) rp[base + 2] = ex; ex += v2;
    if (base + 3 < n) rp[base + 3] = ex;
}

__global__ __launch_bounds__(256) void k_scan2(int* __restrict__ blk, int nblk) {
    __shared__ int sd[256];
    int t = threadIdx.x;
    int v = (t < nblk) ? blk[t] : 0;
    sd[t] = v;
    __syncthreads();
    for (int off = 1; off < 256; off <<= 1) {
        int x = (t >= off) ? sd[t - off] : 0;
        __syncthreads();
        sd[t] += x;
        __syncthreads();
    }
    if (t < nblk) blk[t] = sd[t] - v;
}

__global__ __launch_bounds__(256) void k_scan3(int* __restrict__ rp,
                                               const int* __restrict__ blk,
                                               int n) {
    int t = threadIdx.x;
    int base = blockIdx.x * 1024 + t * 4;
    int off = blk[blockIdx.x];
    #pragma unroll
    for (int i = 0; i < 4; i++) {
        int idx = base + i;
        if (idx < n) rp[idx] += off;
    }
}

// ---------------- GEMM: xl = in @ Wl, xr = in @ Wr ----------------
// Round-7 structure (verified: ~20 us/dispatch). x tile staged through LDS
// with fully-coalesced loads; K-loop reads LDS only.
//   block = 64 rows x 128 cols; thread = 4 rows (stride 16) x 8 cols
//   LDS = 32 KB sW + 17 KB sx -> 3 blocks/CU; sW reads broadcast, sx 2-way.

__global__ __launch_bounds__(256) void k_gemm(const float* __restrict__ in,
                                              const float* __restrict__ Wl,
                                              const float* __restrict__ Wr,
                                              float* __restrict__ xl,
                                              float* __restrict__ xr, int n) {
    __shared__ float4 sW[64 * 32];   // [k][jq]: jq<16 -> Wl cols, else Wr
    __shared__ float  sx[64 * 68];   // 64 rows, pad-68 floats (272 B) stride

    int t = threadIdx.x;
    int base = blockIdx.x * 64;

    float4 xs[4];
    int xrow[4], xkq[4];
    #pragma unroll
    for (int s = 0; s < 4; s++) {
        int i = t + 256 * s;           // 1024 float4 = 64 rows x 16 quads
        int row = i >> 4, kq = i & 15;
        int g = base + row;
        if (g > n - 1) g = n - 1;      // clamp: always-valid load, no UB
        xs[s] = *(const float4*)(in + (size_t)g * 64 + kq * 4);
        xrow[s] = row; xkq[s] = kq;
    }
    for (int i = t; i < 2048; i += 256) {
        int k = i >> 5, jg = i & 31;
        const float* src = (jg < 16) ? (Wl + k * 64 + jg * 4)
                                     : (Wr + k * 64 + (jg - 16) * 4);
        sW[i] = *(const float4*)src;
    }
    #pragma unroll
    for (int s = 0; s < 4; s++)
        *(float4*)(sx + xrow[s] * 68 + xkq[s] * 4) = xs[s];
    __syncthreads();

    int rt = t & 15;   // rows rt, rt+16, rt+32, rt+48
    int ct = t >> 4;   // 16 col tiles of 8 cols (2 quads)
    const float* sxp = sx + rt * 68;

    float4 acc[4][2];
    #pragma unroll
    for (int r = 0; r < 4; r++)
        #pragma unroll
        for (int j = 0; j < 2; j++) acc[r][j] = make_float4(0.f, 0.f, 0.f, 0.f);

    #pragma unroll 1
    for (int k0 = 0; k0 < 64; k0 += 4) {
        float4 xv[4];
        #pragma unroll
        for (int r = 0; r < 4; r++)
            xv[r] = *(const float4*)(sxp + r * (16 * 68) + k0);
        #pragma unroll
        for (int kk = 0; kk < 4; kk++) {
            float4 w0 = sW[(k0 + kk) * 32 + ct * 2 + 0];
            float4 w1 = sW[(k0 + kk) * 32 + ct * 2 + 1];
            #pragma unroll
            for (int r = 0; r < 4; r++) {
                float xk = (kk == 0) ? xv[r].x : (kk == 1) ? xv[r].y
                         : (kk == 2) ? xv[r].z : xv[r].w;
                acc[r][0].x += xk * w0.x;
                acc[r][0].y += xk * w0.y;
                acc[r][0].z += xk * w0.z;
                acc[r][0].w += xk * w0.w;
                acc[r][1].x += xk * w1.x;
                acc[r][1].y += xk * w1.y;
                acc[r][1].z += xk * w1.z;
                acc[r][1].w += xk * w1.w;
            }
        }
    }

    float* outh = (ct < 8) ? xl : xr;
    int cq = (ct & 7) * 8;
    #pragma unroll
    for (int r = 0; r < 4; r++) {
        int g = base + rt + 16 * r;
        if (g < n) {
            float* dst = outh + (size_t)g * 64 + cq;
            *(float4*)(dst + 0) = acc[r][0];
            *(float4*)(dst + 4) = acc[r][1];
        }
    }
}

// ---------------- node kernel: no-max softmax GATv2 aggregation ----------------
// One wave per node, lane = h*16 + o. Batch-8 software pipeline.
// Pad-4 segments -> col loads are 2x int4 per batch, no clamp math.
// No online max (logits O(1): p std ~0.5, max ~3 over 4M; fp32 exp safe to 88).
// Tail/pad slots masked with p=-inf -> w=0; pad col=0 gathers row 0 (hot line).

__global__ __launch_bounds__(256) void k_node(const float* __restrict__ xl,
                                              const float* __restrict__ xr,
                                              const int* __restrict__ rp,
                                              const int* __restrict__ deg,
                                              const int* __restrict__ col,
                                              const float* __restrict__ A,
                                              const float* __restrict__ Bv,
                                              float* __restrict__ outp,
                                              int n, int relu) {
    int lane = threadIdx.x & 63;
    int node = blockIdx.x * 4 + (threadIdx.x >> 6);
    if (node >= n) return;
    unsigned lane4 = (unsigned)lane * 4u;

    float xr_d = xr[(size_t)node * 64 + lane];
    float a_l = A[lane] * LOG2E;   // exp2-domain logits
    float b_l = Bv[lane];

    int start = rp[node];          // multiple of 4 -> 16B-aligned col reads
    int d = deg[node];
    int nb = (d + 7) >> 3;
    const int* cp = col + start;
    const char* xlb = (const char*)xl;

    float den = 0.f, acc = 0.f;

    auto batch = [&](const float (&v)[8], int valid) {
        float p[8];
        #pragma unroll
        for (int j = 0; j < 8; j++) {
            float s = v[j] + xr_d;
            s = fmaxf(s, SLOPE * s);      // leaky_relu (slope < 1)
            float q = s * a_l;
            q = DPP_ADD(q, 0xB1);         // xor1
            q = DPP_ADD(q, 0x4E);         // xor2  -> quad sums
            q = DPP_ADD(q, 0x141);        // half_mirror
            q = DPP_ADD(q, 0x140);        // mirror -> full 16-lane sum
            p[j] = q;
        }
        if (valid < 8) {                  // wave-uniform; tail only
            #pragma unroll
            for (int j = 0; j < 8; j++)
                if (j >= valid) p[j] = -INFINITY;
        }
        #pragma unroll
        for (int j = 0; j < 8; j++) {
            float w = exp2f(p[j]);        // masked: exp2(-inf)=0
            den += w;
            acc += w * v[j];
        }
    };

    float v[8];
    if (nb > 0) {
        int c[8];
        *(int4*)(c + 0) = *(const int4*)(cp + 0);
        *(int4*)(c + 4) = *(const int4*)(cp + 4);
        #pragma unroll
        for (int j = 0; j < 8; j++)
            v[j] = *(const float*)(xlb + ((unsigned)c[j] + lane4));
    }

    #pragma unroll 1
    for (int b = 0; b < nb - 1; b++) {
        int cN[8];
        float vN[8];
        const int* q = cp + (b + 1) * 8;
        *(int4*)(cN + 0) = *(const int4*)(q + 0);
        *(int4*)(cN + 4) = *(const int4*)(q + 4);
        #pragma unroll
        for (int j = 0; j < 8; j++)
            vN[j] = *(const float*)(xlb + ((unsigned)cN[j] + lane4));

        batch(v, 8);                      // full batch: no masking

        #pragma unroll
        for (int j = 0; j < 8; j++) v[j] = vN[j];
    }

    if (nb > 0) {
        batch(v, d - (nb - 1) * 8);       // 1..8 valid in tail
    }

    float o = acc / (den + 1e-16f) + b_l;
    if (relu) o = fmaxf(o, 0.f);
    outp[(size_t)node * 64 + lane] = o;
}

// ---------------- launcher ----------------

extern "C" void kernel_launch(void* const* d_in, const int* in_sizes, int n_in,
                              void* d_out, int out_size, void* d_ws, size_t ws_size,
                              hipStream_t stream) {
    const float* x = (const float*)d_in[0];
    const int* ei = (const int*)d_in[1];
    int N = in_sizes[0] / 64;
    int E = in_sizes[1] / 2;

    const float* Wl[3] = {(const float*)d_in[2], (const float*)d_in[6], (const float*)d_in[10]};
    const float* Wr[3] = {(const float*)d_in[3], (const float*)d_in[7], (const float*)d_in[11]};
    const float* Av[3] = {(const float*)d_in[4], (const float*)d_in[8], (const float*)d_in[12]};
    const float* Bv[3] = {(const float*)d_in[5], (const float*)d_in[9], (const float*)d_in[13]};

    char* w = (char*)d_ws;
    auto carve = [&](size_t bytes) {
        void* p = (void*)w;
        w += (bytes + 255) & ~(size_t)255;
        return p;
    };
    int NBK    = (N + NPB - 1) / NPB;               // buckets of 256 nodes
    int NBLK_E = (E + EPB - 1) / EPB;               // sort blocks of 8192 edges
    size_t histN = (size_t)NBK * NBLK_E;
    size_t colN = (size_t)E + 3 * (size_t)N + 64;   // pad-4 segments + tail slack
    float* xl    = (float*)carve((size_t)N * 64 * 4);
    float* xr    = (float*)carve((size_t)N * 64 * 4);
    float* h     = (float*)carve((size_t)N * 64 * 4);
    int*   rp    = (int*)carve((size_t)N * 4);
    int*   deg   = (int*)carve((size_t)N * 4);
    int*   col   = (int*)carve(colN * 4);
    int*   pairs = (int*)carve((size_t)E * 4);
    int*   hist  = (int*)carve(histN * 4);
    int*   hs    = (int*)carve(histN * 4);
    int*   blk   = (int*)carve(256 * 4);
    int*   blkB  = (int*)carve(256 * 4);

    int nblk1024 = (N + 1023) / 1024;
    int nblkH1024 = (int)((histN + 1023) / 1024);
    int gemm_grid = (N + 63) / 64;
    int node_grid = (N + 3) / 4;

    hipMemsetAsync(col, 0, colN * 4, stream);   // zeroed padding -> safe masked gathers

    // counting sort by dst bucket (no contended global atomics anywhere)
    kH1<<<NBLK_E, 256, 0, stream>>>(ei, hist, E, NBK, NBLK_E);
    k_scan1<<<nblkH1024, 256, 0, stream>>>(hist, hs, blkB, (int)histN, 0);
    k_scan2<<<1, 256, 0, stream>>>(blkB, nblkH1024);
    k_scan3<<<nblkH1024, 256, 0, stream>>>(hs, blkB, (int)histN);
    kH2<<<NBLK_E, 256, 0, stream>>>(ei, hs, pairs, E, NBK, NBLK_E);

    // degrees + row pointers + placement
    kB3<<<NBK, 256, 0, stream>>>(hs, pairs, deg, E, NBK, NBLK_E, N);
    k_scan1<<<nblk1024, 256, 0, stream>>>(deg, rp, blk, N, 1);
    k_scan2<<<1, 256, 0, stream>>>(blk, nblk1024);
    k_scan3<<<nblk1024, 256, 0, stream>>>(rp, blk, N);
    kB4<<<NBK, 256, 0, stream>>>(hs, pairs, rp, col, E, NBK, NBLK_E, N);

    const float* in_l = x;
    for (int l = 0; l < 3; l++) {
        float* out_l = (l == 2) ? (float*)d_out : h;
        int relu = (l < 2) ? 1 : 0;
        k_gemm<<<gemm_grid, 256, 0, stream>>>(in_l, Wl[l], Wr[l], xl, xr, N);
        k_node<<<node_grid, 256, 0, stream>>>(xl, xr, rp, deg, col, Av[l], Bv[l],
                                              out_l, N, relu);
        in_l = h;
    }
}

// Round 5
// 379.534 us; speedup vs baseline: 1.6203x; 1.0549x over previous
//
#include <hip/hip_runtime.h>
#include <math.h>

#define SLOPE 0.2f
#define LOG2E 1.4426950408889634f

// DPP add over 16-lane head group: quad_perm xor1/xor2, row_half_mirror, row_mirror.
#define DPP_ADD(x, ctrl) \
    ((x) + __int_as_float(__builtin_amdgcn_update_dpp( \
        0, __float_as_int(x), (ctrl), 0xF, 0xF, true)))

// ============ CSR build: counting-sort binning (round-9/10) ============
// Two-pass counting sort, no contended global atomics (round-3 lesson:
// 782-cursor global atomics = 237us of cross-XCD serialization).
//   kH1: per-block LDS histogram of dst>>8 -> hist[bucket][block]
//   scan(hist) -> disjoint output runs per (block,bucket)
//   kH2: re-read edges, claim rank via LDS atomic, write pairs[run+rank]
//   kB3: per-bucket padded totals (LDS hist) -> btot
//   kscanB: 1-block chunked exclusive scan of btot -> bbase
//   kB4: rebuild LDS hist + 256-wide LDS prefix -> writes rp/deg AND places
//        col into the bucket's ~10-16KB window (round-10: folds the N-wide
//        deg-scan trio into the bucket pass; 2 fewer dispatches).
// pairs = (src<<8)|(dst&255); col = p & ~255 recovers pre-scaled byte offset.

#define NPB 256               // nodes per bucket (dst >> 8)
#define EPB 8192              // edges per sort block
#define MAXBK 2048            // LDS histogram capacity (N up to 512k)

__global__ __launch_bounds__(256) void kH1(const int* __restrict__ ei,
                                           int* __restrict__ hist,
                                           int E, int nbk, int nblkE) {
    __shared__ int h[MAXBK];
    int t = threadIdx.x, b = blockIdx.x;
    for (int i = t; i < nbk; i += 256) h[i] = 0;
    __syncthreads();
    int e0 = b * EPB, e1 = min(e0 + EPB, E);
    for (int e = e0 + t; e < e1; e += 256)
        atomicAdd(&h[ei[E + e] >> 8], 1);
    __syncthreads();
    for (int i = t; i < nbk; i += 256)
        hist[i * nblkE + b] = h[i];   // hist area ~190KB: stays in L2
}

__global__ __launch_bounds__(256) void kH2(const int* __restrict__ ei,
                                           const int* __restrict__ hs,
                                           int* __restrict__ pairs,
                                           int E, int nbk, int nblkE) {
    __shared__ int soff[MAXBK];       // this block's run starts; LDS-claimed
    int t = threadIdx.x, b = blockIdx.x;
    for (int i = t; i < nbk; i += 256) soff[i] = hs[i * nblkE + b];
    __syncthreads();
    int e0 = b * EPB, e1 = min(e0 + EPB, E);
    for (int e = e0 + t; e < e1; e += 256) {
        int s = ei[e], d = ei[E + e];
        int slot = atomicAdd(&soff[d >> 8], 1);   // LDS atomic: no contention
        pairs[slot] = (s << 8) | (d & (NPB - 1));
    }
}

// kB3: per-bucket PADDED edge total (pad4 per node for k_node's int4 reads).
__global__ __launch_bounds__(256) void kB3(const int* __restrict__ hs,
                                           const int* __restrict__ pairs,
                                           int* __restrict__ btot,
                                           int E, int nbk, int nblkE) {
    __shared__ int sdeg[NPB];
    __shared__ int red[256];
    int t = threadIdx.x, b = blockIdx.x;
    sdeg[t] = 0;
    __syncthreads();
    int s0 = hs[b * nblkE];
    int s1 = (b + 1 < nbk) ? hs[(b + 1) * nblkE] : E;
    for (int i = s0 + t; i < s1; i += 256)
        atomicAdd(&sdeg[pairs[i] & (NPB - 1)], 1);
    __syncthreads();
    red[t] = (sdeg[t] + 3) & ~3;
    __syncthreads();
    for (int off = 128; off; off >>= 1) {
        if (t < off) red[t] += red[t + off];
        __syncthreads();
    }
    if (t == 0) btot[b] = red[0];
}

// kscanB: single-block chunked exclusive scan (nbk up to a few thousand).
__global__ __launch_bounds__(256) void kscanB(const int* __restrict__ btot,
                                              int* __restrict__ bbase, int nbk) {
    __shared__ int sd[256];
    __shared__ int carry;
    int t = threadIdx.x;
    if (t == 0) carry = 0;
    __syncthreads();
    for (int base = 0; base < nbk; base += 256) {
        int v = (base + t < nbk) ? btot[base + t] : 0;
        sd[t] = v;
        __syncthreads();
        for (int off = 1; off < 256; off <<= 1) {
            int x = (t >= off) ? sd[t - off] : 0;
            __syncthreads();
            sd[t] += x;
            __syncthreads();
        }
        if (base + t < nbk) bbase[base + t] = sd[t] - v + carry;
        __syncthreads();
        if (t == 255) carry += sd[255];
        __syncthreads();
    }
}

// kB4: rebuild LDS hist, 256-wide padded prefix -> rp/deg; place col with
// LDS cursors (writes confined to the bucket's window -> full-line dirtying).
__global__ __launch_bounds__(256) void kB4(const int* __restrict__ hs,
                                           const int* __restrict__ pairs,
                                           const int* __restrict__ bbase,
                                           int* __restrict__ rp,
                                           int* __restrict__ deg,
                                           int* __restrict__ col,
                                           int E, int nbk, int nblkE, int n) {
    __shared__ int sdeg[NPB];
    __shared__ int spfx[NPB];
    int t = threadIdx.x, b = blockIdx.x;
    sdeg[t] = 0;
    __syncthreads();
    int s0 = hs[b * nblkE];
    int s1 = (b + 1 < nbk) ? hs[(b + 1) * nblkE] : E;
    for (int i = s0 + t; i < s1; i += 256)
        atomicAdd(&sdeg[pairs[i] & (NPB - 1)], 1);
    __syncthreads();
    int cnt = sdeg[t];
    int pv = (cnt + 3) & ~3;
    spfx[t] = pv;
    __syncthreads();
    for (int off = 1; off < 256; off <<= 1) {
        int x = (t >= off) ? spfx[t - off] : 0;
        __syncthreads();
        spfx[t] += x;
        __syncthreads();
    }
    int rpt = bbase[b] + spfx[t] - pv;
    int node = b * NPB + t;
    if (node < n) { rp[node] = rpt; deg[node] = cnt; }
    __syncthreads();
    sdeg[t] = rpt;                 // reuse as placement cursor
    __syncthreads();
    for (int i = s0 + t; i < s1; i += 256) {
        int p = pairs[i];
        int slot = atomicAdd(&sdeg[p & (NPB - 1)], 1);
        col[slot] = p & ~(NPB - 1);   // recover src<<8
    }
}

// ---------------- scans (hist offsets) ----------------

__global__ __launch_bounds__(256) void k_scan1(const int* __restrict__ deg,
                                               int* __restrict__ rp,
                                               int* __restrict__ blk, int n) {
    __shared__ int sd[256];
    int t = threadIdx.x;
    int base = blockIdx.x * 1024 + t * 4;
    int v0 = 0, v1 = 0, v2 = 0, v3 = 0;
    if (base + 0 < n) v0 = deg[base + 0];
    if (base + 1 < n) v1 = deg[base + 1];
    if (base + 2 < n) v2 = deg[base + 2];
    if (base + 3 < n) v3 = deg[base + 3];
    int s = v0 + v1 + v2 + v3;
    sd[t] = s;
    __syncthreads();
    for (int off = 1; off < 256; off <<= 1) {
        int x = (t >= off) ? sd[t - off] : 0;
        __syncthreads();
        sd[t] += x;
        __syncthreads();
    }
    int ex = sd[t] - s;
    if (t == 255) blk[blockIdx.x] = sd[255];
    if (base + 0 < n) rp[base + 0] = ex; ex += v0;
    if (base + 1 < n) rp[base + 1] = ex; ex += v1;
    if (base + 2 < n) rp[base + 2] = ex; ex += v2;
    if (base + 3 < n) rp[base + 3] = ex;
}

__global__ __launch_bounds__(256) void k_scan2(int* __restrict__ blk, int nblk) {
    __shared__ int sd[256];
    int t = threadIdx.x;
    int v = (t < nblk) ? blk[t] : 0;
    sd[t] = v;
    __syncthreads();
    for (int off = 1; off < 256; off <<= 1) {
        int x = (t >= off) ? sd[t - off] : 0;
        __syncthreads();
        sd[t] += x;
        __syncthreads();
    }
    if (t < nblk) blk[t] = sd[t] - v;
}

__global__ __launch_bounds__(256) void k_scan3(int* __restrict__ rp,
                                               const int* __restrict__ blk,
                                               int n) {
    int t = threadIdx.x;
    int base = blockIdx.x * 1024 + t * 4;
    int off = blk[blockIdx.x];
    #pragma unroll
    for (int i = 0; i < 4; i++) {
        int idx = base + i;
        if (idx < n) rp[idx] += off;
    }
}

// ---------------- GEMM: xl = in @ Wl, xr = in @ Wr ----------------
// Round-7 structure (verified). x tile staged through LDS with fully-
// coalesced loads; K-loop reads LDS only.
//   block = 64 rows x 128 cols; thread = 4 rows (stride 16) x 8 cols
//   LDS = 32 KB sW + 17 KB sx -> 3 blocks/CU; sW reads broadcast, sx 2-way.

__global__ __launch_bounds__(256) void k_gemm(const float* __restrict__ in,
                                              const float* __restrict__ Wl,
                                              const float* __restrict__ Wr,
                                              float* __restrict__ xl,
                                              float* __restrict__ xr, int n) {
    __shared__ float4 sW[64 * 32];   // [k][jq]: jq<16 -> Wl cols, else Wr
    __shared__ float  sx[64 * 68];   // 64 rows, pad-68 floats (272 B) stride

    int t = threadIdx.x;
    int base = blockIdx.x * 64;

    float4 xs[4];
    int xrow[4], xkq[4];
    #pragma unroll
    for (int s = 0; s < 4; s++) {
        int i = t + 256 * s;           // 1024 float4 = 64 rows x 16 quads
        int row = i >> 4, kq = i & 15;
        int g = base + row;
        if (g > n - 1) g = n - 1;      // clamp: always-valid load, no UB
        xs[s] = *(const float4*)(in + (size_t)g * 64 + kq * 4);
        xrow[s] = row; xkq[s] = kq;
    }
    for (int i = t; i < 2048; i += 256) {
        int k = i >> 5, jg = i & 31;
        const float* src = (jg < 16) ? (Wl + k * 64 + jg * 4)
                                     : (Wr + k * 64 + (jg - 16) * 4);
        sW[i] = *(const float4*)src;
    }
    #pragma unroll
    for (int s = 0; s < 4; s++)
        *(float4*)(sx + xrow[s] * 68 + xkq[s] * 4) = xs[s];
    __syncthreads();

    int rt = t & 15;   // rows rt, rt+16, rt+32, rt+48
    int ct = t >> 4;   // 16 col tiles of 8 cols (2 quads)
    const float* sxp = sx + rt * 68;

    float4 acc[4][2];
    #pragma unroll
    for (int r = 0; r < 4; r++)
        #pragma unroll
        for (int j = 0; j < 2; j++) acc[r][j] = make_float4(0.f, 0.f, 0.f, 0.f);

    #pragma unroll 1
    for (int k0 = 0; k0 < 64; k0 += 4) {
        float4 xv[4];
        #pragma unroll
        for (int r = 0; r < 4; r++)
            xv[r] = *(const float4*)(sxp + r * (16 * 68) + k0);
        #pragma unroll
        for (int kk = 0; kk < 4; kk++) {
            float4 w0 = sW[(k0 + kk) * 32 + ct * 2 + 0];
            float4 w1 = sW[(k0 + kk) * 32 + ct * 2 + 1];
            #pragma unroll
            for (int r = 0; r < 4; r++) {
                float xk = (kk == 0) ? xv[r].x : (kk == 1) ? xv[r].y
                         : (kk == 2) ? xv[r].z : xv[r].w;
                acc[r][0].x += xk * w0.x;
                acc[r][0].y += xk * w0.y;
                acc[r][0].z += xk * w0.z;
                acc[r][0].w += xk * w0.w;
                acc[r][1].x += xk * w1.x;
                acc[r][1].y += xk * w1.y;
                acc[r][1].z += xk * w1.z;
                acc[r][1].w += xk * w1.w;
            }
        }
    }

    float* outh = (ct < 8) ? xl : xr;
    int cq = (ct & 7) * 8;
    #pragma unroll
    for (int r = 0; r < 4; r++) {
        int g = base + rt + 16 * r;
        if (g < n) {
            float* dst = outh + (size_t)g * 64 + cq;
            *(float4*)(dst + 0) = acc[r][0];
            *(float4*)(dst + 4) = acc[r][1];
        }
    }
}

// ---------------- node kernel: no-max softmax GATv2 aggregation ----------------
// One wave per node, lane = h*16 + o. Batch-8 software pipeline.
// Round-10: node is readfirstlane'd -> the compiler can prove rp/deg/cp and
// the col int4 loads wave-UNIFORM: scalar loop bounds, s_load'ed col words,
// SALU gather bases. Round-4 showed VALUBusy 96% with ~3.5x more issue than
// the math needs -- the excess was divergent-typed address/control overhead.
// exp2 via __builtin_amdgcn_exp2f = raw v_exp_f32 (no denorm fixup chain);
// exp2(-inf)=0 still masks tail/pad slots.

__global__ __launch_bounds__(256) void k_node(const float* __restrict__ xl,
                                              const float* __restrict__ xr,
                                              const int* __restrict__ rp,
                                              const int* __restrict__ deg,
                                              const int* __restrict__ col,
                                              const float* __restrict__ A,
                                              const float* __restrict__ Bv,
                                              float* __restrict__ outp,
                                              int n, int relu) {
    int lane = threadIdx.x & 63;
    int node = __builtin_amdgcn_readfirstlane(blockIdx.x * 4 + (threadIdx.x >> 6));
    if (node >= n) return;             // scalar branch
    unsigned lane4 = (unsigned)lane * 4u;

    float xr_d = xr[(size_t)node * 64 + lane];
    float a_l = A[lane] * LOG2E;       // exp2-domain logits
    float b_l = Bv[lane];

    int start = rp[node];              // uniform -> s_load
    int d = deg[node];                 // uniform -> s_load
    int nb = (d + 7) >> 3;
    const int* cp = col + start;       // uniform pointer -> s_load_dwordx4
    const char* xlb = (const char*)xl;

    float den = 0.f, acc = 0.f;

    auto batch = [&](const float (&v)[8], int valid) {
        float p[8];
        #pragma unroll
        for (int j = 0; j < 8; j++) {
            float s = v[j] + xr_d;
            s = fmaxf(s, SLOPE * s);      // leaky_relu (slope < 1)
            float q = s * a_l;
            q = DPP_ADD(q, 0xB1);         // xor1
            q = DPP_ADD(q, 0x4E);         // xor2  -> quad sums
            q = DPP_ADD(q, 0x141);        // half_mirror
            q = DPP_ADD(q, 0x140);        // mirror -> full 16-lane sum
            p[j] = q;
        }
        if (valid < 8) {                  // wave-uniform; tail only
            #pragma unroll
            for (int j = 0; j < 8; j++)
                if (j >= valid) p[j] = -INFINITY;
        }
        #pragma unroll
        for (int j = 0; j < 8; j++) {
            float w = __builtin_amdgcn_exp2f(p[j]);   // masked: exp2(-inf)=0
            den += w;
            acc += w * v[j];
        }
    };

    float v[8];
    if (nb > 0) {
        int c[8];
        *(int4*)(c + 0) = *(const int4*)(cp + 0);
        *(int4*)(c + 4) = *(const int4*)(cp + 4);
        #pragma unroll
        for (int j = 0; j < 8; j++)
            v[j] = *(const float*)(xlb + ((unsigned)c[j] + lane4));
    }

    #pragma unroll 1
    for (int b = 0; b < nb - 1; b++) {
        int cN[8];
        float vN[8];
        const int* q = cp + (b + 1) * 8;
        *(int4*)(cN + 0) = *(const int4*)(q + 0);
        *(int4*)(cN + 4) = *(const int4*)(q + 4);
        #pragma unroll
        for (int j = 0; j < 8; j++)
            vN[j] = *(const float*)(xlb + ((unsigned)cN[j] + lane4));

        batch(v, 8);                      // full batch: no masking

        #pragma unroll
        for (int j = 0; j < 8; j++) v[j] = vN[j];
    }

    if (nb > 0) {
        batch(v, d - (nb - 1) * 8);       // 1..8 valid in tail
    }

    float o = acc / (den + 1e-16f) + b_l;
    if (relu) o = fmaxf(o, 0.f);
    outp[(size_t)node * 64 + lane] = o;
}

// ---------------- launcher ----------------

extern "C" void kernel_launch(void* const* d_in, const int* in_sizes, int n_in,
                              void* d_out, int out_size, void* d_ws, size_t ws_size,
                              hipStream_t stream) {
    const float* x = (const float*)d_in[0];
    const int* ei = (const int*)d_in[1];
    int N = in_sizes[0] / 64;
    int E = in_sizes[1] / 2;

    const float* Wl[3] = {(const float*)d_in[2], (const float*)d_in[6], (const float*)d_in[10]};
    const float* Wr[3] = {(const float*)d_in[3], (const float*)d_in[7], (const float*)d_in[11]};
    const float* Av[3] = {(const float*)d_in[4], (const float*)d_in[8], (const float*)d_in[12]};
    const float* Bv[3] = {(const float*)d_in[5], (const float*)d_in[9], (const float*)d_in[13]};

    char* w = (char*)d_ws;
    auto carve = [&](size_t bytes) {
        void* p = (void*)w;
        w += (bytes + 255) & ~(size_t)255;
        return p;
    };
    int NBK    = (N + NPB - 1) / NPB;               // buckets of 256 nodes
    int NBLK_E = (E + EPB - 1) / EPB;               // sort blocks of 8192 edges
    size_t histN = (size_t)NBK * NBLK_E;
    size_t colN = (size_t)E + 3 * (size_t)N + 64;   // pad-4 segments + tail slack
    float* xl    = (float*)carve((size_t)N * 64 * 4);
    float* xr    = (float*)carve((size_t)N * 64 * 4);
    float* h     = (float*)carve((size_t)N * 64 * 4);
    int*   rp    = (int*)carve((size_t)N * 4);
    int*   deg   = (int*)carve((size_t)N * 4);
    int*   col   = (int*)carve(colN * 4);
    int*   pairs = (int*)carve((size_t)E * 4);
    int*   hist  = (int*)carve(histN * 4);
    int*   hs    = (int*)carve(histN * 4);
    int*   btot  = (int*)carve((size_t)NBK * 4);
    int*   bbase = (int*)carve((size_t)NBK * 4);
    int*   blkB  = (int*)carve(256 * 4);

    int nblkH1024 = (int)((histN + 1023) / 1024);
    int gemm_grid = (N + 63) / 64;
    int node_grid = (N + 3) / 4;

    hipMemsetAsync(col, 0, colN * 4, stream);   // zeroed padding -> safe masked gathers

    // counting sort by dst bucket (no contended global atomics anywhere)
    kH1<<<NBLK_E, 256, 0, stream>>>(ei, hist, E, NBK, NBLK_E);
    k_scan1<<<nblkH1024, 256, 0, stream>>>(hist, hs, blkB, (int)histN);
    k_scan2<<<1, 256, 0, stream>>>(blkB, nblkH1024);
    k_scan3<<<nblkH1024, 256, 0, stream>>>(hs, blkB, (int)histN);
    kH2<<<NBLK_E, 256, 0, stream>>>(ei, hs, pairs, E, NBK, NBLK_E);

    // per-bucket: padded totals -> bucket bases -> rp/deg/col in one pass
    kB3<<<NBK, 256, 0, stream>>>(hs, pairs, btot, E, NBK, NBLK_E);
    kscanB<<<1, 256, 0, stream>>>(btot, bbase, NBK);
    kB4<<<NBK, 256, 0, stream>>>(hs, pairs, bbase, rp, deg, col, E, NBK, NBLK_E, N);

    const float* in_l = x;
    for (int l = 0; l < 3; l++) {
        float* out_l = (l == 2) ? (float*)d_out : h;
        int relu = (l < 2) ? 1 : 0;
        k_gemm<<<gemm_grid, 256, 0, stream>>>(in_l, Wl[l], Wr[l], xl, xr, N);
        k_node<<<node_grid, 256, 0, stream>>>(xl, xr, rp, deg, col, Av[l], Bv[l],
                                              out_l, N, relu);
        in_l = h;
    }
}

// Round 6
// 359.615 us; speedup vs baseline: 1.7100x; 1.0554x over previous
//
#include <hip/hip_runtime.h>
#include <math.h>

#define SLOPE 0.2f
#define LOG2E 1.4426950408889634f

// DPP add over lane groups: quad_perm xor1/xor2, row_half_mirror.
#define DPP_ADD(x, ctrl) \
    ((x) + __int_as_float(__builtin_amdgcn_update_dpp( \
        0, __float_as_int(x), (ctrl), 0xF, 0xF, true)))

// ============ CSR build: counting-sort binning (round-9/10) ============
// Two-pass counting sort, no contended global atomics (round-3 lesson:
// 782-cursor global atomics = 237us of cross-XCD serialization).
//   kH1: per-block LDS histogram of dst>>8 -> hist[bucket][block]
//   scan(hist) -> disjoint output runs per (block,bucket)
//   kH2: re-read edges, claim rank via LDS atomic, write pairs[run+rank]
//   kB3: per-bucket padded totals (LDS hist) -> btot
//   kscanB: 1-block chunked exclusive scan of btot -> bbase
//   kB4: rebuild LDS hist + 256-wide LDS prefix -> rp/deg + col placement.
// pairs = (src<<8)|(dst&255); col = p & ~255 recovers pre-scaled byte offset.

#define NPB 256               // nodes per bucket (dst >> 8)
#define EPB 8192              // edges per sort block
#define MAXBK 2048            // LDS histogram capacity (N up to 512k)

__global__ __launch_bounds__(256) void kH1(const int* __restrict__ ei,
                                           int* __restrict__ hist,
                                           int E, int nbk, int nblkE) {
    __shared__ int h[MAXBK];
    int t = threadIdx.x, b = blockIdx.x;
    for (int i = t; i < nbk; i += 256) h[i] = 0;
    __syncthreads();
    int e0 = b * EPB, e1 = min(e0 + EPB, E);
    for (int e = e0 + t; e < e1; e += 256)
        atomicAdd(&h[ei[E + e] >> 8], 1);
    __syncthreads();
    for (int i = t; i < nbk; i += 256)
        hist[i * nblkE + b] = h[i];   // hist area ~190KB: stays in L2
}

__global__ __launch_bounds__(256) void kH2(const int* __restrict__ ei,
                                           const int* __restrict__ hs,
                                           int* __restrict__ pairs,
                                           int E, int nbk, int nblkE) {
    __shared__ int soff[MAXBK];       // this block's run starts; LDS-claimed
    int t = threadIdx.x, b = blockIdx.x;
    for (int i = t; i < nbk; i += 256) soff[i] = hs[i * nblkE + b];
    __syncthreads();
    int e0 = b * EPB, e1 = min(e0 + EPB, E);
    for (int e = e0 + t; e < e1; e += 256) {
        int s = ei[e], d = ei[E + e];
        int slot = atomicAdd(&soff[d >> 8], 1);   // LDS atomic: no contention
        pairs[slot] = (s << 8) | (d & (NPB - 1));
    }
}

// kB3: per-bucket PADDED edge total (pad4 per node for k_node's int4 reads).
__global__ __launch_bounds__(256) void kB3(const int* __restrict__ hs,
                                           const int* __restrict__ pairs,
                                           int* __restrict__ btot,
                                           int E, int nbk, int nblkE) {
    __shared__ int sdeg[NPB];
    __shared__ int red[256];
    int t = threadIdx.x, b = blockIdx.x;
    sdeg[t] = 0;
    __syncthreads();
    int s0 = hs[b * nblkE];
    int s1 = (b + 1 < nbk) ? hs[(b + 1) * nblkE] : E;
    for (int i = s0 + t; i < s1; i += 256)
        atomicAdd(&sdeg[pairs[i] & (NPB - 1)], 1);
    __syncthreads();
    red[t] = (sdeg[t] + 3) & ~3;
    __syncthreads();
    for (int off = 128; off; off >>= 1) {
        if (t < off) red[t] += red[t + off];
        __syncthreads();
    }
    if (t == 0) btot[b] = red[0];
}

// kscanB: single-block chunked exclusive scan (nbk up to a few thousand).
__global__ __launch_bounds__(256) void kscanB(const int* __restrict__ btot,
                                              int* __restrict__ bbase, int nbk) {
    __shared__ int sd[256];
    __shared__ int carry;
    int t = threadIdx.x;
    if (t == 0) carry = 0;
    __syncthreads();
    for (int base = 0; base < nbk; base += 256) {
        int v = (base + t < nbk) ? btot[base + t] : 0;
        sd[t] = v;
        __syncthreads();
        for (int off = 1; off < 256; off <<= 1) {
            int x = (t >= off) ? sd[t - off] : 0;
            __syncthreads();
            sd[t] += x;
            __syncthreads();
        }
        if (base + t < nbk) bbase[base + t] = sd[t] - v + carry;
        __syncthreads();
        if (t == 255) carry += sd[255];
        __syncthreads();
    }
}

// kB4: rebuild LDS hist, 256-wide padded prefix -> rp/deg; place col with
// LDS cursors (writes confined to the bucket's window -> full-line dirtying).
__global__ __launch_bounds__(256) void kB4(const int* __restrict__ hs,
                                           const int* __restrict__ pairs,
                                           const int* __restrict__ bbase,
                                           int* __restrict__ rp,
                                           int* __restrict__ deg,
                                           int* __restrict__ col,
                                           int E, int nbk, int nblkE, int n) {
    __shared__ int sdeg[NPB];
    __shared__ int spfx[NPB];
    int t = threadIdx.x, b = blockIdx.x;
    sdeg[t] = 0;
    __syncthreads();
    int s0 = hs[b * nblkE];
    int s1 = (b + 1 < nbk) ? hs[(b + 1) * nblkE] : E;
    for (int i = s0 + t; i < s1; i += 256)
        atomicAdd(&sdeg[pairs[i] & (NPB - 1)], 1);
    __syncthreads();
    int cnt = sdeg[t];
    int pv = (cnt + 3) & ~3;
    spfx[t] = pv;
    __syncthreads();
    for (int off = 1; off < 256; off <<= 1) {
        int x = (t >= off) ? spfx[t - off] : 0;
        __syncthreads();
        spfx[t] += x;
        __syncthreads();
    }
    int rpt = bbase[b] + spfx[t] - pv;
    int node = b * NPB + t;
    if (node < n) { rp[node] = rpt; deg[node] = cnt; }
    __syncthreads();
    sdeg[t] = rpt;                 // reuse as placement cursor
    __syncthreads();
    for (int i = s0 + t; i < s1; i += 256) {
        int p = pairs[i];
        int slot = atomicAdd(&sdeg[p & (NPB - 1)], 1);
        col[slot] = p & ~(NPB - 1);   // recover src<<8
    }
}

// ---------------- scans (hist offsets) ----------------

__global__ __launch_bounds__(256) void k_scan1(const int* __restrict__ deg,
                                               int* __restrict__ rp,
                                               int* __restrict__ blk, int n) {
    __shared__ int sd[256];
    int t = threadIdx.x;
    int base = blockIdx.x * 1024 + t * 4;
    int v0 = 0, v1 = 0, v2 = 0, v3 = 0;
    if (base + 0 < n) v0 = deg[base + 0];
    if (base + 1 < n) v1 = deg[base + 1];
    if (base + 2 < n) v2 = deg[base + 2];
    if (base + 3 < n) v3 = deg[base + 3];
    int s = v0 + v1 + v2 + v3;
    sd[t] = s;
    __syncthreads();
    for (int off = 1; off < 256; off <<= 1) {
        int x = (t >= off) ? sd[t - off] : 0;
        __syncthreads();
        sd[t] += x;
        __syncthreads();
    }
    int ex = sd[t] - s;
    if (t == 255) blk[blockIdx.x] = sd[255];
    if (base + 0 < n) rp[base + 0] = ex; ex += v0;
    if (base + 1 < n) rp[base + 1] = ex; ex += v1;
    if (base + 2 < n) rp[base + 2] = ex; ex += v2;
    if (base + 3 < n) rp[base + 3] = ex;
}

__global__ __launch_bounds__(256) void k_scan2(int* __restrict__ blk, int nblk) {
    __shared__ int sd[256];
    int t = threadIdx.x;
    int v = (t < nblk) ? blk[t] : 0;
    sd[t] = v;
    __syncthreads();
    for (int off = 1; off < 256; off <<= 1) {
        int x = (t >= off) ? sd[t - off] : 0;
        __syncthreads();
        sd[t] += x;
        __syncthreads();
    }
    if (t < nblk) blk[t] = sd[t] - v;
}

__global__ __launch_bounds__(256) void k_scan3(int* __restrict__ rp,
                                               const int* __restrict__ blk,
                                               int n) {
    int t = threadIdx.x;
    int base = blockIdx.x * 1024 + t * 4;
    int off = blk[blockIdx.x];
    #pragma unroll
    for (int i = 0; i < 4; i++) {
        int idx = base + i;
        if (idx < n) rp[idx] += off;
    }
}

// ---------------- GEMM: xl = in @ Wl, xr = in @ Wr ----------------
// Round-7 structure (verified). x tile staged through LDS with fully-
// coalesced loads; K-loop reads LDS only.
//   block = 64 rows x 128 cols; thread = 4 rows (stride 16) x 8 cols
//   LDS = 32 KB sW + 17 KB sx -> 3 blocks/CU; sW reads broadcast, sx 2-way.

__global__ __launch_bounds__(256) void k_gemm(const float* __restrict__ in,
                                              const float* __restrict__ Wl,
                                              const float* __restrict__ Wr,
                                              float* __restrict__ xl,
                                              float* __restrict__ xr, int n) {
    __shared__ float4 sW[64 * 32];   // [k][jq]: jq<16 -> Wl cols, else Wr
    __shared__ float  sx[64 * 68];   // 64 rows, pad-68 floats (272 B) stride

    int t = threadIdx.x;
    int base = blockIdx.x * 64;

    float4 xs[4];
    int xrow[4], xkq[4];
    #pragma unroll
    for (int s = 0; s < 4; s++) {
        int i = t + 256 * s;           // 1024 float4 = 64 rows x 16 quads
        int row = i >> 4, kq = i & 15;
        int g = base + row;
        if (g > n - 1) g = n - 1;      // clamp: always-valid load, no UB
        xs[s] = *(const float4*)(in + (size_t)g * 64 + kq * 4);
        xrow[s] = row; xkq[s] = kq;
    }
    for (int i = t; i < 2048; i += 256) {
        int k = i >> 5, jg = i & 31;
        const float* src = (jg < 16) ? (Wl + k * 64 + jg * 4)
                                     : (Wr + k * 64 + (jg - 16) * 4);
        sW[i] = *(const float4*)src;
    }
    #pragma unroll
    for (int s = 0; s < 4; s++)
        *(float4*)(sx + xrow[s] * 68 + xkq[s] * 4) = xs[s];
    __syncthreads();

    int rt = t & 15;   // rows rt, rt+16, rt+32, rt+48
    int ct = t >> 4;   // 16 col tiles of 8 cols (2 quads)
    const float* sxp = sx + rt * 68;

    float4 acc[4][2];
    #pragma unroll
    for (int r = 0; r < 4; r++)
        #pragma unroll
        for (int j = 0; j < 2; j++) acc[r][j] = make_float4(0.f, 0.f, 0.f, 0.f);

    #pragma unroll 1
    for (int k0 = 0; k0 < 64; k0 += 4) {
        float4 xv[4];
        #pragma unroll
        for (int r = 0; r < 4; r++)
            xv[r] = *(const float4*)(sxp + r * (16 * 68) + k0);
        #pragma unroll
        for (int kk = 0; kk < 4; kk++) {
            float4 w0 = sW[(k0 + kk) * 32 + ct * 2 + 0];
            float4 w1 = sW[(k0 + kk) * 32 + ct * 2 + 1];
            #pragma unroll
            for (int r = 0; r < 4; r++) {
                float xk = (kk == 0) ? xv[r].x : (kk == 1) ? xv[r].y
                         : (kk == 2) ? xv[r].z : xv[r].w;
                acc[r][0].x += xk * w0.x;
                acc[r][0].y += xk * w0.y;
                acc[r][0].z += xk * w0.z;
                acc[r][0].w += xk * w0.w;
                acc[r][1].x += xk * w1.x;
                acc[r][1].y += xk * w1.y;
                acc[r][1].z += xk * w1.z;
                acc[r][1].w += xk * w1.w;
            }
        }
    }

    float* outh = (ct < 8) ? xl : xr;
    int cq = (ct & 7) * 8;
    #pragma unroll
    for (int r = 0; r < 4; r++) {
        int g = base + rt + 16 * r;
        if (g < n) {
            float* dst = outh + (size_t)g * 64 + cq;
            *(float4*)(dst + 0) = acc[r][0];
            *(float4*)(dst + 4) = acc[r][1];
        }
    }
}

// ---------------- node kernel: no-max softmax GATv2 aggregation ----------------
// Round-11 restructure: round-5 was still VALU-issue-bound (VALUBusy 72%,
// HBM 41%) at ~17 wave-instr/edge. Now each lane holds a float2 (2 channels):
// a head = 8 lanes, a node = 32 lanes, and the two wave halves process TWO
// edges of the same node simultaneously (grp 0 = even edge, grp 1 = odd).
//   - gather: 1 dwordx2/pair (half the load instrs, same bytes)
//   - elementwise math packed (v_pk_*_f32), dot h-add + 3-step DPP tree
//     (xor1, xor2, half_mirror over 8 lanes), each instr covers 2 edges
//   - exp2/den once per PAIR; epilogue: one shfl_xor(32) combine per node
// ~8 wave-instr/edge vs 17. Still: scalar node (readfirstlane), raw v_exp_f32,
// pad-4 col int4 scalar loads, tail masked with q=-inf (exp2(-inf)=0).

__global__ __launch_bounds__(256) void k_node(const float* __restrict__ xl,
                                              const float* __restrict__ xr,
                                              const int* __restrict__ rp,
                                              const int* __restrict__ deg,
                                              const int* __restrict__ col,
                                              const float* __restrict__ A,
                                              const float* __restrict__ Bv,
                                              float* __restrict__ outp,
                                              int n, int relu) {
    int lane = threadIdx.x & 63;
    int node = __builtin_amdgcn_readfirstlane(blockIdx.x * 4 + (threadIdx.x >> 6));
    if (node >= n) return;             // scalar branch
    int grp = lane >> 5;               // 0: even edges, 1: odd edges
    int s   = lane & 31;
    int chn = ((s >> 3) << 4) + ((s & 7) << 1);   // h*16 + o2*2
    unsigned cofs = (unsigned)chn * 4u;           // byte offset within a row

    float2 xr2 = *(const float2*)(xr + (size_t)node * 64 + chn);
    float2 a2  = *(const float2*)(A + chn);
    a2.x *= LOG2E; a2.y *= LOG2E;      // exp2-domain logits
    float2 b2  = *(const float2*)(Bv + chn);

    int start = rp[node];              // uniform -> s_load
    int d = deg[node];
    int nb = (d + 7) >> 3;             // batches of 8 edges = 4 pairs
    const int* cp = col + start;
    const char* xlb = (const char*)xl;

    float den = 0.f;
    float ax = 0.f, ay = 0.f;

    auto batch = [&](const float2 (&v)[4], int ebase, bool full) {
        #pragma unroll
        for (int j = 0; j < 4; j++) {
            float sx_ = v[j].x + xr2.x;
            float sy_ = v[j].y + xr2.y;
            sx_ = fmaxf(sx_, SLOPE * sx_);        // leaky_relu (slope < 1)
            sy_ = fmaxf(sy_, SLOPE * sy_);
            float q = sx_ * a2.x + sy_ * a2.y;    // per-lane partial dot
            q = DPP_ADD(q, 0xB1);                 // xor1
            q = DPP_ADD(q, 0x4E);                 // xor2 -> quad sums
            q = DPP_ADD(q, 0x141);                // half_mirror -> 8-lane sum
            if (!full) {
                int eidx = ebase + 2 * j + grp;   // per-lane; tail only
                if (eidx >= d) q = -INFINITY;
            }
            float w = __builtin_amdgcn_exp2f(q);  // masked: exp2(-inf)=0
            den += w;
            ax += w * v[j].x;
            ay += w * v[j].y;
        }
    };

    auto gather = [&](float2 (&v)[4], const int* q) {
        int c[8];
        *(int4*)(c + 0) = *(const int4*)(q + 0);  // uniform -> s_load
        *(int4*)(c + 4) = *(const int4*)(q + 4);
        #pragma unroll
        for (int j = 0; j < 4; j++) {
            unsigned cc = (unsigned)(grp ? c[2 * j + 1] : c[2 * j]);
            v[j] = *(const float2*)(xlb + (cc + cofs));
        }
    };

    float2 v[4];
    if (nb > 0) gather(v, cp);

    #pragma unroll 1
    for (int b = 0; b < nb - 1; b++) {
        float2 vN[4];
        gather(vN, cp + (b + 1) * 8);
        batch(v, b * 8, true);                    // full: no masking
        #pragma unroll
        for (int j = 0; j < 4; j++) v[j] = vN[j];
    }
    if (nb > 0) batch(v, (nb - 1) * 8, false);    // tail: mask eidx >= d

    // combine the two halves (even-edge and odd-edge partials)
    den += __shfl_xor(den, 32, 64);
    ax  += __shfl_xor(ax, 32, 64);
    ay  += __shfl_xor(ay, 32, 64);

    float inv = 1.f / (den + 1e-16f);
    float ox = ax * inv + b2.x;
    float oy = ay * inv + b2.y;
    if (relu) { ox = fmaxf(ox, 0.f); oy = fmaxf(oy, 0.f); }
    if (grp == 0)
        *(float2*)(outp + (size_t)node * 64 + chn) = make_float2(ox, oy);
}

// ---------------- launcher ----------------

extern "C" void kernel_launch(void* const* d_in, const int* in_sizes, int n_in,
                              void* d_out, int out_size, void* d_ws, size_t ws_size,
                              hipStream_t stream) {
    const float* x = (const float*)d_in[0];
    const int* ei = (const int*)d_in[1];
    int N = in_sizes[0] / 64;
    int E = in_sizes[1] / 2;

    const float* Wl[3] = {(const float*)d_in[2], (const float*)d_in[6], (const float*)d_in[10]};
    const float* Wr[3] = {(const float*)d_in[3], (const float*)d_in[7], (const float*)d_in[11]};
    const float* Av[3] = {(const float*)d_in[4], (const float*)d_in[8], (const float*)d_in[12]};
    const float* Bv[3] = {(const float*)d_in[5], (const float*)d_in[9], (const float*)d_in[13]};

    char* w = (char*)d_ws;
    auto carve = [&](size_t bytes) {
        void* p = (void*)w;
        w += (bytes + 255) & ~(size_t)255;
        return p;
    };
    int NBK    = (N + NPB - 1) / NPB;               // buckets of 256 nodes
    int NBLK_E = (E + EPB - 1) / EPB;               // sort blocks of 8192 edges
    size_t histN = (size_t)NBK * NBLK_E;
    size_t colN = (size_t)E + 3 * (size_t)N + 64;   // pad-4 segments + tail slack
    float* xl    = (float*)carve((size_t)N * 64 * 4);
    float* xr    = (float*)carve((size_t)N * 64 * 4);
    float* h     = (float*)carve((size_t)N * 64 * 4);
    int*   rp    = (int*)carve((size_t)N * 4);
    int*   deg   = (int*)carve((size_t)N * 4);
    int*   col   = (int*)carve(colN * 4);
    int*   pairs = (int*)carve((size_t)E * 4);
    int*   hist  = (int*)carve(histN * 4);
    int*   hs    = (int*)carve(histN * 4);
    int*   btot  = (int*)carve((size_t)NBK * 4);
    int*   bbase = (int*)carve((size_t)NBK * 4);
    int*   blkB  = (int*)carve(256 * 4);

    int nblkH1024 = (int)((histN + 1023) / 1024);
    int gemm_grid = (N + 63) / 64;
    int node_grid = (N + 3) / 4;

    hipMemsetAsync(col, 0, colN * 4, stream);   // zeroed padding -> safe masked gathers

    // counting sort by dst bucket (no contended global atomics anywhere)
    kH1<<<NBLK_E, 256, 0, stream>>>(ei, hist, E, NBK, NBLK_E);
    k_scan1<<<nblkH1024, 256, 0, stream>>>(hist, hs, blkB, (int)histN);
    k_scan2<<<1, 256, 0, stream>>>(blkB, nblkH1024);
    k_scan3<<<nblkH1024, 256, 0, stream>>>(hs, blkB, (int)histN);
    kH2<<<NBLK_E, 256, 0, stream>>>(ei, hs, pairs, E, NBK, NBLK_E);

    // per-bucket: padded totals -> bucket bases -> rp/deg/col in one pass
    kB3<<<NBK, 256, 0, stream>>>(hs, pairs, btot, E, NBK, NBLK_E);
    kscanB<<<1, 256, 0, stream>>>(btot, bbase, NBK);
    kB4<<<NBK, 256, 0, stream>>>(hs, pairs, bbase, rp, deg, col, E, NBK, NBLK_E, N);

    const float* in_l = x;
    for (int l = 0; l < 3; l++) {
        float* out_l = (l == 2) ? (float*)d_out : h;
        int relu = (l < 2) ? 1 : 0;
        k_gemm<<<gemm_grid, 256, 0, stream>>>(in_l, Wl[l], Wr[l], xl, xr, N);
        k_node<<<node_grid, 256, 0, stream>>>(xl, xr, rp, deg, col, Av[l], Bv[l],
                                              out_l, N, relu);
        in_l = h;
    }
}